// Round 3
// baseline (221.433 us; speedup 1.0000x reference)
//
#include <hip/hip_runtime.h>
#include <hip/hip_bf16.h>

// Problem constants
#define NN 100000
#define DD 128
#define BB 4096
#define KK 64
#define HH 256
#define EE 128

typedef __bf16 bf16x8 __attribute__((ext_vector_type(8)));
typedef float f32x4 __attribute__((ext_vector_type(4)));

// ---- bf16 frag region (element offsets into __bf16* base) ----
// each frag = 64 lanes x 16B = 1KB = 512 bf16 elems
#define EL_W1A 0        // 16nt x 4kk = 64 frags
#define EL_W1B 32768    // 8nt x 8kk  = 64 frags
#define EL_WIH 65536    // 64nt x 4kk = 256 frags
#define EL_WHH 196608   // 64nt x 8kk = 512 frags
#define EL_W3  458752   // 8nt x 8kk  = 64 frags
#define EL_W2B 491520   // 16nt x 4kk = 64 frags
#define EL_W2A 524288   // 16nt x 4kk = 64 frags
// frag region ends at elem 557056 = byte 0x110000

// ---- fp32 / bf16 workspace regions (byte offsets) ----
#define BOFF_GB     0x110000   // fp32[1024]  bih+bhh
#define BOFF_W1COL  0x111000   // fp32[256]   W1a[:,128]
#define BOFF_W2COL  0x111400   // fp32[256]   W2a[:,128]
#define BOFF_CONST  0x111800   // fp32[4096]
#define BOFF_T      0x115800   // t bf16[4096][256] (2MB)

__device__ __forceinline__ float sigmoid_f(float x){ return 1.0f/(1.0f+__expf(-x)); }
__device__ __forceinline__ float tanh_f(float x){ return 1.0f - 2.0f/(__expf(2.0f*x)+1.0f); }

__device__ __forceinline__ bf16x8 pack8(float4 a, float4 b){
    bf16x8 v;
    v[0]=(__bf16)a.x; v[1]=(__bf16)a.y; v[2]=(__bf16)a.z; v[3]=(__bf16)a.w;
    v[4]=(__bf16)b.x; v[5]=(__bf16)b.y; v[6]=(__bf16)b.z; v[7]=(__bf16)b.w;
    return v;
}

// ---------------- weight swizzle + misc precompute -------------------------
// B-frag layout for mfma_f32_16x16x32_bf16: lane l holds B[k][n] with
// n = nt*16 + (l&15), k = kk*32 + (l>>4)*8 + j, j=0..7.
__global__ __launch_bounds__(64) void swz_kernel(
    const float* __restrict__ W1a, const float* __restrict__ W1b,
    const float* __restrict__ Wih, const float* __restrict__ Whh,
    const float* __restrict__ W3,  const float* __restrict__ W2b,
    const float* __restrict__ W2a, const float* __restrict__ bih,
    const float* __restrict__ bhh, __bf16* __restrict__ wsbf,
    float* __restrict__ gb_ws, float* __restrict__ w1col_ws,
    float* __restrict__ w2col_ws)
{
    int g = blockIdx.x, lane = threadIdx.x;
    if (g >= 1088){
        if (g < 1104){ int idx = (g-1088)*64 + lane; gb_ws[idx] = bih[idx] + bhh[idx]; }
        else if (g < 1108){ int idx = (g-1104)*64 + lane; w1col_ws[idx] = W1a[idx*129 + 128]; }
        else { int idx = (g-1108)*64 + lane; w2col_ws[idx] = W2a[idx*129 + 128]; }
        return;
    }
    int quad = lane >> 4, l15 = lane & 15;
    const float* src; int stride, nkk, local; long dst; bool kn = false;
    if      (g <  64){ src=W1a; stride=129; nkk=4; dst=EL_W1A; local=g;      }
    else if (g < 128){ src=W1b; stride=256; nkk=8; dst=EL_W1B; local=g-64;   }
    else if (g < 384){ src=Wih; stride=128; nkk=4; dst=EL_WIH; local=g-128;  }
    else if (g < 896){ src=Whh; stride=256; nkk=8; dst=EL_WHH; local=g-384;  }
    else if (g < 960){ src=W3;  stride=256; nkk=8; dst=EL_W3;  local=g-896;  }
    else if (g <1024){ src=W2b; stride=256; nkk=4; dst=EL_W2B; local=g-960; kn=true; }
    else             { src=W2a; stride=129; nkk=4; dst=EL_W2A; local=g-1024; }
    int nt = local / nkk, kk = local % nkk;
    int n = nt*16 + l15, k0 = kk*32 + quad*8;
    bf16x8 v;
#pragma unroll
    for (int j = 0; j < 8; ++j){
        float x = kn ? src[(long)(k0+j)*stride + n] : src[(long)n*stride + k0 + j];
        v[j] = (__bf16)x;
    }
    ((bf16x8*)(wsbf + dst))[local*64 + lane] = v;
}

// ---------------- fused action path: MLP1 -> LSTM -> MLP3 -> t -------------
// 256 blocks x 256 threads; block = 16 batch rows (one 16-row M-tile).
// All 4 waves share the M-tile and split the N dimension.
__global__ __launch_bounds__(256) void act_kernel(
    const float* __restrict__ node_pre, const float* __restrict__ steps,
    const float* __restrict__ h0, const float* __restrict__ c0_in,
    const float* __restrict__ b1a, const float* __restrict__ b1b,
    const float* __restrict__ b3, const float* __restrict__ b2b,
    const int* __restrict__ actions0, const float* __restrict__ gb_ws,
    const float* __restrict__ w1col, const __bf16* __restrict__ wsbf,
    float* __restrict__ out_h, float* __restrict__ out_c,
    __bf16* __restrict__ t_bf, float* __restrict__ const_ws)
{
    __shared__ __bf16 apre[16*136];   // a_pre -> x -> emb (stride 136)
    __shared__ __bf16 x1s [16*264];   // x1 -> h_new (stride 264)
    __shared__ __bf16 h0s [16*264];   // h0 bf16
    __shared__ float b1a_s[256], w1c_s[256], b1b_s[128], gbs[1024];
    __shared__ float b3_s[128], b2b_s[128], sb_s[16];

    int tid = threadIdx.x, b0 = blockIdx.x * 16;
    b1a_s[tid] = b1a[tid];
    w1c_s[tid] = w1col[tid];
    if (tid < 128){ b1b_s[tid] = b1b[tid]; b3_s[tid] = b3[tid]; b2b_s[tid] = b2b[tid]; }
    for (int ch = tid; ch < 1024; ch += 256) gbs[ch] = gb_ws[ch];
    if (tid < 16) sb_s[tid] = steps[b0 + tid] * 0.01f;
    {   // gather a_pre: 16 threads/row x 8 floats
        int r = tid >> 4, seg = tid & 15;
        long a0 = actions0[b0 + r];
        const float4* sp = (const float4*)(node_pre + a0*128 + seg*8);
        float4 f0 = sp[0], f1 = sp[1];
        *(bf16x8*)&apre[r*136 + seg*8] = pack8(f0, f1);
    }
    // stage h0 -> bf16 LDS
    for (int ch = tid; ch < 512; ch += 256){
        int r = ch >> 5, sg = ch & 31;
        const float4* sp = (const float4*)(h0 + (long)(b0+r)*256 + sg*8);
        float4 a = sp[0], b = sp[1];
        *(bf16x8*)&h0s[r*264 + sg*8] = pack8(a, b);
    }
    __syncthreads();

    int wave = tid >> 6, lane = tid & 63, quad = lane >> 4, l15 = lane & 15;
    const bf16x8* F1A = (const bf16x8*)(wsbf + EL_W1A);
    const bf16x8* F1B = (const bf16x8*)(wsbf + EL_W1B);
    const bf16x8* FIH = (const bf16x8*)(wsbf + EL_WIH);
    const bf16x8* FHH = (const bf16x8*)(wsbf + EL_WHH);
    const bf16x8* F3  = (const bf16x8*)(wsbf + EL_W3);
    const bf16x8* F2B = (const bf16x8*)(wsbf + EL_W2B);

    // S1: x1 = relu(a_pre @ W1a^T + b1a + w1col*sb), N=256 K=128
    {
        bf16x8 af[4];
#pragma unroll
        for (int kk = 0; kk < 4; ++kk)
            af[kk] = *(const bf16x8*)&apre[l15*136 + kk*32 + quad*8];
#pragma unroll
        for (int j = 0; j < 4; ++j){
            int nt = wave*4 + j;
            f32x4 acc = {0.f,0.f,0.f,0.f};
#pragma unroll
            for (int kk = 0; kk < 4; ++kk)
                acc = __builtin_amdgcn_mfma_f32_16x16x32_bf16(af[kk], F1A[(nt*4+kk)*64 + lane], acc, 0,0,0);
            int col = nt*16 + l15;
            float bb = b1a_s[col], wc = w1c_s[col];
#pragma unroll
            for (int i = 0; i < 4; ++i){
                int r = quad*4 + i;
                x1s[r*264 + col] = (__bf16)fmaxf(acc[i] + bb + wc*sb_s[r], 0.f);
            }
        }
    }
    __syncthreads();

    // S2: x = x1 @ W1b^T + b1b, N=128 K=256 -> apre (stride 136)
    {
        bf16x8 af[8];
#pragma unroll
        for (int kk = 0; kk < 8; ++kk)
            af[kk] = *(const bf16x8*)&x1s[l15*264 + kk*32 + quad*8];
#pragma unroll
        for (int j = 0; j < 2; ++j){
            int nt = wave*2 + j;
            f32x4 acc = {0.f,0.f,0.f,0.f};
#pragma unroll
            for (int kk = 0; kk < 8; ++kk)
                acc = __builtin_amdgcn_mfma_f32_16x16x32_bf16(af[kk], F1B[(nt*8+kk)*64 + lane], acc, 0,0,0);
            int col = nt*16 + l15;
#pragma unroll
            for (int i = 0; i < 4; ++i)
                apre[(quad*4+i)*136 + col] = (__bf16)(acc[i] + b1b_s[col]);
        }
    }
    __syncthreads();

    // S3: gates = [x|h0] @ [Wih|Whh]^T + gb; LSTM elementwise
    {
        bf16x8 af[12];
#pragma unroll
        for (int kk = 0; kk < 4; ++kk)
            af[kk] = *(const bf16x8*)&apre[l15*136 + kk*32 + quad*8];
#pragma unroll
        for (int kk = 0; kk < 8; ++kk)
            af[4+kk] = *(const bf16x8*)&h0s[l15*264 + kk*32 + quad*8];

#pragma unroll 1
        for (int jj = 0; jj < 4; ++jj){
            int ct = wave*4 + jj;                // col-tile within a gate (0..15)
            f32x4 aI = {0.f,0.f,0.f,0.f}, aF = aI, aG = aI, aO = aI;
#pragma unroll
            for (int kk = 0; kk < 4; ++kk){
                aI = __builtin_amdgcn_mfma_f32_16x16x32_bf16(af[kk], FIH[(( 0+ct)*4+kk)*64 + lane], aI, 0,0,0);
                aF = __builtin_amdgcn_mfma_f32_16x16x32_bf16(af[kk], FIH[((16+ct)*4+kk)*64 + lane], aF, 0,0,0);
                aG = __builtin_amdgcn_mfma_f32_16x16x32_bf16(af[kk], FIH[((32+ct)*4+kk)*64 + lane], aG, 0,0,0);
                aO = __builtin_amdgcn_mfma_f32_16x16x32_bf16(af[kk], FIH[((48+ct)*4+kk)*64 + lane], aO, 0,0,0);
            }
#pragma unroll 4
            for (int k2 = 0; k2 < 8; ++k2){
                aI = __builtin_amdgcn_mfma_f32_16x16x32_bf16(af[4+k2], FHH[(( 0+ct)*8+k2)*64 + lane], aI, 0,0,0);
                aF = __builtin_amdgcn_mfma_f32_16x16x32_bf16(af[4+k2], FHH[((16+ct)*8+k2)*64 + lane], aF, 0,0,0);
                aG = __builtin_amdgcn_mfma_f32_16x16x32_bf16(af[4+k2], FHH[((32+ct)*8+k2)*64 + lane], aG, 0,0,0);
                aO = __builtin_amdgcn_mfma_f32_16x16x32_bf16(af[4+k2], FHH[((48+ct)*8+k2)*64 + lane], aO, 0,0,0);
            }
            int col = ct*16 + l15;
            float bI = gbs[col], bF = gbs[256+col], bG = gbs[512+col], bO = gbs[768+col];
#pragma unroll
            for (int i = 0; i < 4; ++i){
                long row = b0 + quad*4 + i;
                float iv = aI[i]+bI, fv = aF[i]+bF, gv = aG[i]+bG, ov = aO[i]+bO;
                float cc = c0_in[row*256 + col];
                float cn = sigmoid_f(fv)*cc + sigmoid_f(iv)*tanh_f(gv);
                float hn = sigmoid_f(ov)*tanh_f(cn);
                out_c[row*256 + col] = cn;
                out_h[row*256 + col] = hn;
                x1s[(quad*4+i)*264 + col] = (__bf16)hn;   // h_new for S4
            }
        }
    }
    __syncthreads();

    // S4: emb = h @ W3^T + b3, N=128 K=256 -> apre (stride 136)
    {
        bf16x8 af[8];
#pragma unroll
        for (int kk = 0; kk < 8; ++kk)
            af[kk] = *(const bf16x8*)&x1s[l15*264 + kk*32 + quad*8];
#pragma unroll
        for (int j = 0; j < 2; ++j){
            int nt = wave*2 + j;
            f32x4 acc = {0.f,0.f,0.f,0.f};
#pragma unroll
            for (int kk = 0; kk < 8; ++kk)
                acc = __builtin_amdgcn_mfma_f32_16x16x32_bf16(af[kk], F3[(nt*8+kk)*64 + lane], acc, 0,0,0);
            int col = nt*16 + l15;
#pragma unroll
            for (int i = 0; i < 4; ++i)
                apre[(quad*4+i)*136 + col] = (__bf16)(acc[i] + b3_s[col]);
        }
    }
    __syncthreads();

    // const[b] = dot(b2b, emb[b])
    {
        int r = tid >> 4, p = tid & 15;
        float s = 0.f;
#pragma unroll
        for (int q = 0; q < 8; ++q) s += b2b_s[p*8+q] * (float)apre[r*136 + p*8 + q];
#pragma unroll
        for (int m = 1; m < 16; m <<= 1) s += __shfl_xor(s, m, 64);
        if (p == 0) const_ws[b0 + r] = s;
    }
    // S5: t = W2b^T emb, N=256 K=128 -> bf16 global
    {
        bf16x8 ef[4];
#pragma unroll
        for (int kk = 0; kk < 4; ++kk)
            ef[kk] = *(const bf16x8*)&apre[l15*136 + kk*32 + quad*8];
#pragma unroll
        for (int j = 0; j < 4; ++j){
            int nt = wave*4 + j;
            f32x4 acc = {0.f,0.f,0.f,0.f};
#pragma unroll
            for (int kk = 0; kk < 4; ++kk)
                acc = __builtin_amdgcn_mfma_f32_16x16x32_bf16(ef[kk], F2B[(nt*4+kk)*64 + lane], acc, 0,0,0);
            int col = nt*16 + l15;
#pragma unroll
            for (int i = 0; i < 4; ++i)
                t_bf[(long)(b0 + quad*4 + i)*256 + col] = (__bf16)acc[i];
        }
    }
}

// ---------------- neighbor path: 4 batch rows per block --------------------
// deg-aware: only ceil(deg/16) of the 4 M-tiles are gathered/computed.
__global__ __launch_bounds__(256) void nei_kernel(
    const float* __restrict__ node_pre, const float* __restrict__ steps,
    const float* __restrict__ b2a, const float* __restrict__ w2col,
    const int* __restrict__ neighbors, const int* __restrict__ deg,
    const __bf16* __restrict__ wsbf, const __bf16* __restrict__ t_bf,
    const float* __restrict__ const_ws, float* __restrict__ out_vals)
{
    __shared__ __bf16 at[64*136];
    __shared__ float t_s[256], b2a_s[256], w2c_s[256], vp[256];

    int tid = threadIdx.x, blk = blockIdx.x;
    b2a_s[tid] = b2a[tid];
    w2c_s[tid] = w2col[tid];

    int wave = tid >> 6, lane = tid & 63, quad = lane >> 4, l15 = lane & 15;
    const bf16x8* FB = (const bf16x8*)(wsbf + EL_W2A);
    bf16x8 bw[16];   // wave's 4 n-tiles x 4 k-steps, held in registers
#pragma unroll
    for (int j = 0; j < 4; ++j){
        int nt = wave + 4*j;
#pragma unroll
        for (int kk = 0; kk < 4; ++kk) bw[j*4+kk] = FB[(nt*4+kk)*64 + lane];
    }

#pragma unroll 1
    for (int ib = 0; ib < 4; ++ib){
        int b = blk*4 + ib;
        __syncthreads();   // protect at/t_s/vp from previous iteration readers
        int degb = deg[b]; if (degb < 1) degb = 1;
        int ntile = (degb + 15) >> 4;            // active 16-row M-tiles (1..4)
        t_s[tid] = (float)t_bf[(long)b*256 + tid];
        {   // gather only active rows (fp32 -> bf16 LDS, stride 136)
            int r = tid >> 2, sg = tid & 3;
            if (r < ntile*16){
                long nb = neighbors[b*64 + r];
                const float4* sp = (const float4*)(node_pre + nb*128 + sg*32);
#pragma unroll
                for (int q = 0; q < 4; ++q){
                    float4 fa = sp[q*2], fb = sp[q*2+1];
                    *(bf16x8*)&at[r*136 + sg*32 + q*8] = pack8(fa, fb);
                }
            }
        }
        __syncthreads();

        float sb = steps[b] * 0.01f;
#pragma unroll 1
        for (int mt = 0; mt < ntile; ++mt){
            bf16x8 af[4];
#pragma unroll
            for (int kk = 0; kk < 4; ++kk)
                af[kk] = *(const bf16x8*)&at[(mt*16 + l15)*136 + kk*32 + quad*8];
            f32x4 ps = {0.f,0.f,0.f,0.f};
#pragma unroll
            for (int j = 0; j < 4; ++j){
                int nt = wave + 4*j;
                f32x4 acc = {0.f,0.f,0.f,0.f};
#pragma unroll
                for (int kk = 0; kk < 4; ++kk)
                    acc = __builtin_amdgcn_mfma_f32_16x16x32_bf16(af[kk], bw[j*4+kk], acc, 0,0,0);
                int col = nt*16 + l15;
                float bb = b2a_s[col] + w2c_s[col]*sb;
                float tv = t_s[col];
#pragma unroll
                for (int i = 0; i < 4; ++i)
                    ps[i] += fmaxf(acc[i] + bb, 0.f) * tv;
            }
#pragma unroll
            for (int m = 1; m < 16; m <<= 1){
#pragma unroll
                for (int i = 0; i < 4; ++i) ps[i] += __shfl_xor(ps[i], m, 64);
            }
            if (l15 == 0){
#pragma unroll
                for (int i = 0; i < 4; ++i) vp[wave*64 + mt*16 + quad*4 + i] = ps[i];
            }
        }
        __syncthreads();
        if (tid < 64){
            // rows >= ntile*16 read stale vp but are masked to 0 below
            float v = vp[tid] + vp[64+tid] + vp[128+tid] + vp[192+tid];
            v = (v + const_ws[b]) * 0.08838834764831845f;   // 1/sqrt(128)
            if (tid >= degb) v = 0.f;
            out_vals[(long)b*64 + tid] = v;
        }
    }
}

extern "C" void kernel_launch(void* const* d_in, const int* in_sizes, int n_in,
                              void* d_out, int out_size, void* d_ws, size_t ws_size,
                              hipStream_t stream)
{
    (void)in_sizes; (void)n_in; (void)out_size; (void)ws_size;
    const float* node_pre = (const float*)d_in[0];
    const float* steps    = (const float*)d_in[1];
    const float* h0       = (const float*)d_in[2];
    const float* c0       = (const float*)d_in[3];
    const float* W1a      = (const float*)d_in[4];
    const float* b1a      = (const float*)d_in[5];
    const float* W1b      = (const float*)d_in[6];
    const float* b1b      = (const float*)d_in[7];
    const float* W2a      = (const float*)d_in[8];
    const float* b2a      = (const float*)d_in[9];
    const float* W2b      = (const float*)d_in[10];
    const float* b2b      = (const float*)d_in[11];
    const float* W3       = (const float*)d_in[12];
    const float* b3       = (const float*)d_in[13];
    const float* Wih      = (const float*)d_in[14];
    const float* Whh      = (const float*)d_in[15];
    const float* bih      = (const float*)d_in[16];
    const float* bhh      = (const float*)d_in[17];
    const int* actions0   = (const int*)d_in[18];
    const int* neighbors  = (const int*)d_in[19];
    const int* deg        = (const int*)d_in[20];

    float* out      = (float*)d_out;
    float* out_vals = out;                       // [4096][64]
    float* out_h    = out + (long)BB*KK;         // [4096][256]
    float* out_c    = out_h + (long)BB*HH;       // [4096][256]

    __bf16* wsbf     = (__bf16*)d_ws;
    float* gb_ws     = (float*)((char*)d_ws + BOFF_GB);
    float* w1col_ws  = (float*)((char*)d_ws + BOFF_W1COL);
    float* w2col_ws  = (float*)((char*)d_ws + BOFF_W2COL);
    float* const_ws  = (float*)((char*)d_ws + BOFF_CONST);
    __bf16* t_bf     = (__bf16*)((char*)d_ws + BOFF_T);

    swz_kernel<<<dim3(1112), dim3(64), 0, stream>>>(W1a, W1b, Wih, Whh, W3, W2b, W2a,
                                                    bih, bhh, wsbf, gb_ws, w1col_ws, w2col_ws);
    act_kernel<<<dim3(256), dim3(256), 0, stream>>>(node_pre, steps, h0, c0, b1a, b1b, b3, b2b,
                                                    actions0, gb_ws, w1col_ws, wsbf,
                                                    out_h, out_c, t_bf, const_ws);
    nei_kernel<<<dim3(1024), dim3(256), 0, stream>>>(node_pre, steps, b2a, w2col_ws,
                                                     neighbors, deg, wsbf, t_bf, const_ws,
                                                     out_vals);
}

// Round 4
// 181.367 us; speedup vs baseline: 1.2209x; 1.2209x over previous
//
#include <hip/hip_runtime.h>
#include <hip/hip_bf16.h>

// Problem constants
#define NN 100000
#define DD 128
#define BB 4096
#define KK 64
#define HH 256
#define EE 128

typedef __bf16 bf16x8 __attribute__((ext_vector_type(8)));
typedef float f32x4 __attribute__((ext_vector_type(4)));

// ---- bf16 frag region (element offsets into __bf16* base) ----
// each frag = 64 lanes x 16B = 1KB = 512 bf16 elems
#define EL_W1A 0        // 16nt x 4kk = 64 frags
#define EL_W1B 32768    // 8nt x 8kk  = 64 frags
#define EL_WIH 65536    // 64nt x 4kk = 256 frags
#define EL_WHH 196608   // 64nt x 8kk = 512 frags
#define EL_W3  458752   // 8nt x 8kk  = 64 frags
#define EL_W2B 491520   // 16nt x 4kk = 64 frags
#define EL_W2A 524288   // 16nt x 4kk = 64 frags
// frag region ends at elem 557056 = byte 0x110000

// ---- workspace regions (byte offsets) ----
#define BOFF_GB     0x110000   // fp32[1024]  bih+bhh
#define BOFF_W1COL  0x111000   // fp32[256]   W1a[:,128]
#define BOFF_W2COL  0x111400   // fp32[256]   W2a[:,128]
#define BOFF_CONST  0x111800   // fp32[4096]
#define BOFF_X1     0x115800   // x1  bf16[4096][256] (2MB)
#define BOFF_X      0x315800   // x   bf16[4096][128] (1MB)
#define BOFF_H0B    0x415800   // h0  bf16[4096][256] (2MB)
#define BOFF_HB     0x615800   // h   bf16[4096][256] (2MB)
#define BOFF_EMB    0x815800   // emb bf16[4096][128] (1MB)
#define BOFF_T      0x915800   // t   bf16[4096][256] (2MB)

__device__ __forceinline__ float sigmoid_f(float x){ return 1.0f/(1.0f+__expf(-x)); }
__device__ __forceinline__ float tanh_f(float x){ return 1.0f - 2.0f/(__expf(2.0f*x)+1.0f); }

__device__ __forceinline__ bf16x8 pack8(float4 a, float4 b){
    bf16x8 v;
    v[0]=(__bf16)a.x; v[1]=(__bf16)a.y; v[2]=(__bf16)a.z; v[3]=(__bf16)a.w;
    v[4]=(__bf16)b.x; v[5]=(__bf16)b.y; v[6]=(__bf16)b.z; v[7]=(__bf16)b.w;
    return v;
}

// ---------------- weight swizzle + misc precompute + h0->bf16 --------------
// B-frag layout for mfma_f32_16x16x32_bf16: lane l holds B[k][n] with
// n = nt*16 + (l&15), k = kk*32 + (l>>4)*8 + j, j=0..7.
__global__ __launch_bounds__(64) void swz_kernel(
    const float* __restrict__ W1a, const float* __restrict__ W1b,
    const float* __restrict__ Wih, const float* __restrict__ Whh,
    const float* __restrict__ W3,  const float* __restrict__ W2b,
    const float* __restrict__ W2a, const float* __restrict__ bih,
    const float* __restrict__ bhh, const float* __restrict__ h0,
    __bf16* __restrict__ wsbf, float* __restrict__ gb_ws,
    float* __restrict__ w1col_ws, float* __restrict__ w2col_ws,
    __bf16* __restrict__ h0_bf)
{
    int g = blockIdx.x, lane = threadIdx.x;
    if (g >= 1088){
        if (g < 1104){ int idx = (g-1088)*64 + lane; gb_ws[idx] = bih[idx] + bhh[idx]; }
        else if (g < 1108){ int idx = (g-1104)*64 + lane; w1col_ws[idx] = W1a[idx*129 + 128]; }
        else if (g < 1112){ int idx = (g-1108)*64 + lane; w2col_ws[idx] = W2a[idx*129 + 128]; }
        else {  // h0 fp32 -> bf16: 131072 chunks of 8
            long i = (long)(g-1112)*64 + lane;
            const float4* sp = (const float4*)h0 + i*2;
            ((bf16x8*)h0_bf)[i] = pack8(sp[0], sp[1]);
        }
        return;
    }
    int quad = lane >> 4, l15 = lane & 15;
    const float* src; int stride, nkk, local; long dst; bool kn = false;
    if      (g <  64){ src=W1a; stride=129; nkk=4; dst=EL_W1A; local=g;      }
    else if (g < 128){ src=W1b; stride=256; nkk=8; dst=EL_W1B; local=g-64;   }
    else if (g < 384){ src=Wih; stride=128; nkk=4; dst=EL_WIH; local=g-128;  }
    else if (g < 896){ src=Whh; stride=256; nkk=8; dst=EL_WHH; local=g-384;  }
    else if (g < 960){ src=W3;  stride=256; nkk=8; dst=EL_W3;  local=g-896;  }
    else if (g <1024){ src=W2b; stride=256; nkk=4; dst=EL_W2B; local=g-960; kn=true; }
    else             { src=W2a; stride=129; nkk=4; dst=EL_W2A; local=g-1024; }
    int nt = local / nkk, kk = local % nkk;
    int n = nt*16 + l15, k0 = kk*32 + quad*8;
    bf16x8 v;
#pragma unroll
    for (int j = 0; j < 8; ++j){
        float x = kn ? src[(long)(k0+j)*stride + n] : src[(long)n*stride + k0 + j];
        v[j] = (__bf16)x;
    }
    ((bf16x8*)(wsbf + dst))[local*64 + lane] = v;
}

// ---------------- S1: x1 = relu(a_pre @ W1a^T + b1a + w1col*sb) ------------
// grid 1024 = 256 M-tiles x 4 N-groups; 64 threads (1 wave), 4 ntiles/wave
__global__ __launch_bounds__(64) void s1_kernel(
    const float* __restrict__ node_pre, const float* __restrict__ steps,
    const int* __restrict__ actions0, const float* __restrict__ b1a,
    const float* __restrict__ w1col, const __bf16* __restrict__ wsbf,
    __bf16* __restrict__ x1_bf)
{
    int lane = threadIdx.x, quad = lane >> 4, l15 = lane & 15;
    int mt = blockIdx.x >> 2, ng = blockIdx.x & 3, m0 = mt*16;
    long arow = actions0[m0 + l15];
    bf16x8 af[4];
#pragma unroll
    for (int kk = 0; kk < 4; ++kk){
        const float4* p = (const float4*)(node_pre + arow*128 + kk*32 + quad*8);
        af[kk] = pack8(p[0], p[1]);
    }
    float sb_i[4];
#pragma unroll
    for (int i = 0; i < 4; ++i) sb_i[i] = steps[m0 + quad*4 + i] * 0.01f;
    const bf16x8* FB = (const bf16x8*)(wsbf + EL_W1A);
#pragma unroll
    for (int j = 0; j < 4; ++j){
        int nt = ng*4 + j;
        f32x4 acc = {0.f,0.f,0.f,0.f};
#pragma unroll
        for (int kk = 0; kk < 4; ++kk)
            acc = __builtin_amdgcn_mfma_f32_16x16x32_bf16(af[kk], FB[(nt*4+kk)*64 + lane], acc, 0,0,0);
        int col = nt*16 + l15;
        float bb = b1a[col], wc = w1col[col];
#pragma unroll
        for (int i = 0; i < 4; ++i)
            x1_bf[(long)(m0 + quad*4 + i)*256 + col] = (__bf16)fmaxf(acc[i] + bb + wc*sb_i[i], 0.f);
    }
}

// ---------------- S2: x = x1 @ W1b^T + b1b ---------------------------------
// grid 1024 = 256 x 4; 2 ntiles/wave (N=128)
__global__ __launch_bounds__(64) void s2_kernel(
    const __bf16* __restrict__ x1_bf, const float* __restrict__ b1b,
    const __bf16* __restrict__ wsbf, __bf16* __restrict__ x_bf)
{
    int lane = threadIdx.x, quad = lane >> 4, l15 = lane & 15;
    int mt = blockIdx.x >> 2, ng = blockIdx.x & 3, m0 = mt*16;
    bf16x8 af[8];
#pragma unroll
    for (int kk = 0; kk < 8; ++kk)
        af[kk] = *(const bf16x8*)&x1_bf[(long)(m0 + l15)*256 + kk*32 + quad*8];
    const bf16x8* FB = (const bf16x8*)(wsbf + EL_W1B);
#pragma unroll
    for (int j = 0; j < 2; ++j){
        int nt = ng*2 + j;
        f32x4 acc = {0.f,0.f,0.f,0.f};
#pragma unroll
        for (int kk = 0; kk < 8; ++kk)
            acc = __builtin_amdgcn_mfma_f32_16x16x32_bf16(af[kk], FB[(nt*8+kk)*64 + lane], acc, 0,0,0);
        int col = nt*16 + l15;
        float bb = b1b[col];
#pragma unroll
        for (int i = 0; i < 4; ++i)
            x_bf[(long)(m0 + quad*4 + i)*128 + col] = (__bf16)(acc[i] + bb);
    }
}

// ---------------- S3: LSTM gates + elementwise -----------------------------
// grid 4096 = 256 M-tiles x 16 col-tiles; 1 col-tile/wave, 48 MFMA
__global__ __launch_bounds__(64) void lstm_kernel(
    const __bf16* __restrict__ x_bf, const __bf16* __restrict__ h0_bf,
    const float* __restrict__ c0_in, const float* __restrict__ gb_ws,
    const __bf16* __restrict__ wsbf,
    float* __restrict__ out_h, float* __restrict__ out_c, __bf16* __restrict__ h_bf)
{
    int lane = threadIdx.x, quad = lane >> 4, l15 = lane & 15;
    int mt = blockIdx.x >> 4, ct = blockIdx.x & 15, m0 = mt*16;
    bf16x8 af[12];
#pragma unroll
    for (int kk = 0; kk < 4; ++kk)
        af[kk] = *(const bf16x8*)&x_bf[(long)(m0 + l15)*128 + kk*32 + quad*8];
#pragma unroll
    for (int kk = 0; kk < 8; ++kk)
        af[4+kk] = *(const bf16x8*)&h0_bf[(long)(m0 + l15)*256 + kk*32 + quad*8];

    const bf16x8* FIH = (const bf16x8*)(wsbf + EL_WIH);
    const bf16x8* FHH = (const bf16x8*)(wsbf + EL_WHH);
    f32x4 aI = {0.f,0.f,0.f,0.f}, aF = aI, aG = aI, aO = aI;
#pragma unroll
    for (int kk = 0; kk < 4; ++kk){
        aI = __builtin_amdgcn_mfma_f32_16x16x32_bf16(af[kk], FIH[(( 0+ct)*4+kk)*64 + lane], aI, 0,0,0);
        aF = __builtin_amdgcn_mfma_f32_16x16x32_bf16(af[kk], FIH[((16+ct)*4+kk)*64 + lane], aF, 0,0,0);
        aG = __builtin_amdgcn_mfma_f32_16x16x32_bf16(af[kk], FIH[((32+ct)*4+kk)*64 + lane], aG, 0,0,0);
        aO = __builtin_amdgcn_mfma_f32_16x16x32_bf16(af[kk], FIH[((48+ct)*4+kk)*64 + lane], aO, 0,0,0);
    }
#pragma unroll
    for (int k2 = 0; k2 < 8; ++k2){
        aI = __builtin_amdgcn_mfma_f32_16x16x32_bf16(af[4+k2], FHH[(( 0+ct)*8+k2)*64 + lane], aI, 0,0,0);
        aF = __builtin_amdgcn_mfma_f32_16x16x32_bf16(af[4+k2], FHH[((16+ct)*8+k2)*64 + lane], aF, 0,0,0);
        aG = __builtin_amdgcn_mfma_f32_16x16x32_bf16(af[4+k2], FHH[((32+ct)*8+k2)*64 + lane], aG, 0,0,0);
        aO = __builtin_amdgcn_mfma_f32_16x16x32_bf16(af[4+k2], FHH[((48+ct)*8+k2)*64 + lane], aO, 0,0,0);
    }
    int col = ct*16 + l15;
    float bI = gb_ws[col], bF = gb_ws[256+col], bG = gb_ws[512+col], bO = gb_ws[768+col];
#pragma unroll
    for (int i = 0; i < 4; ++i){
        long row = m0 + quad*4 + i;
        float iv = aI[i]+bI, fv = aF[i]+bF, gv = aG[i]+bG, ov = aO[i]+bO;
        float cc = c0_in[row*256 + col];
        float cn = sigmoid_f(fv)*cc + sigmoid_f(iv)*tanh_f(gv);
        float hn = sigmoid_f(ov)*tanh_f(cn);
        out_c[row*256 + col] = cn;
        out_h[row*256 + col] = hn;
        h_bf[row*256 + col] = (__bf16)hn;
    }
}

// ---------------- S4: emb = h @ W3^T + b3 ----------------------------------
__global__ __launch_bounds__(64) void s4_kernel(
    const __bf16* __restrict__ h_bf, const float* __restrict__ b3,
    const __bf16* __restrict__ wsbf, __bf16* __restrict__ emb_bf)
{
    int lane = threadIdx.x, quad = lane >> 4, l15 = lane & 15;
    int mt = blockIdx.x >> 2, ng = blockIdx.x & 3, m0 = mt*16;
    bf16x8 af[8];
#pragma unroll
    for (int kk = 0; kk < 8; ++kk)
        af[kk] = *(const bf16x8*)&h_bf[(long)(m0 + l15)*256 + kk*32 + quad*8];
    const bf16x8* FB = (const bf16x8*)(wsbf + EL_W3);
#pragma unroll
    for (int j = 0; j < 2; ++j){
        int nt = ng*2 + j;
        f32x4 acc = {0.f,0.f,0.f,0.f};
#pragma unroll
        for (int kk = 0; kk < 8; ++kk)
            acc = __builtin_amdgcn_mfma_f32_16x16x32_bf16(af[kk], FB[(nt*8+kk)*64 + lane], acc, 0,0,0);
        int col = nt*16 + l15;
        float bb = b3[col];
#pragma unroll
        for (int i = 0; i < 4; ++i)
            emb_bf[(long)(m0 + quad*4 + i)*128 + col] = (__bf16)(acc[i] + bb);
    }
}

// ---------------- S5: t = W2b^T emb; const = b2b . emb ---------------------
__global__ __launch_bounds__(64) void s5_kernel(
    const __bf16* __restrict__ emb_bf, const float* __restrict__ b2b,
    const __bf16* __restrict__ wsbf, __bf16* __restrict__ t_bf,
    float* __restrict__ const_ws)
{
    int lane = threadIdx.x, quad = lane >> 4, l15 = lane & 15;
    int mt = blockIdx.x >> 2, ng = blockIdx.x & 3, m0 = mt*16;
    bf16x8 af[4];
#pragma unroll
    for (int kk = 0; kk < 4; ++kk)
        af[kk] = *(const bf16x8*)&emb_bf[(long)(m0 + l15)*128 + kk*32 + quad*8];
    if (ng == 0){
        float s = 0.f;
#pragma unroll
        for (int kk = 0; kk < 4; ++kk)
#pragma unroll
            for (int j = 0; j < 8; ++j)
                s += b2b[kk*32 + quad*8 + j] * (float)af[kk][j];
        s += __shfl_xor(s, 16, 64);
        s += __shfl_xor(s, 32, 64);
        if (lane < 16) const_ws[m0 + l15] = s;
    }
    const bf16x8* FB = (const bf16x8*)(wsbf + EL_W2B);
#pragma unroll
    for (int j = 0; j < 4; ++j){
        int nt = ng*4 + j;
        f32x4 acc = {0.f,0.f,0.f,0.f};
#pragma unroll
        for (int kk = 0; kk < 4; ++kk)
            acc = __builtin_amdgcn_mfma_f32_16x16x32_bf16(af[kk], FB[(nt*4+kk)*64 + lane], acc, 0,0,0);
        int col = nt*16 + l15;
#pragma unroll
        for (int i = 0; i < 4; ++i)
            t_bf[(long)(m0 + quad*4 + i)*256 + col] = (__bf16)acc[i];
    }
}

// ---------------- neighbor path: one batch row per block, deg-aware --------
__global__ __launch_bounds__(256) void nei_kernel(
    const float* __restrict__ node_pre, const float* __restrict__ steps,
    const float* __restrict__ b2a, const float* __restrict__ w2col,
    const int* __restrict__ neighbors, const int* __restrict__ deg,
    const __bf16* __restrict__ wsbf, const __bf16* __restrict__ t_bf,
    const float* __restrict__ const_ws, float* __restrict__ out_vals)
{
    __shared__ __bf16 at[64*136];
    __shared__ float t_s[256], bias_s[256], vp[256];

    int tid = threadIdx.x, b = blockIdx.x;
    int degb = deg[b]; if (degb < 1) degb = 1;
    int ntile = (degb + 15) >> 4;            // active 16-row M-tiles (1..4)
    float sb = steps[b] * 0.01f;
    t_s[tid]    = (float)t_bf[(long)b*256 + tid];
    bias_s[tid] = b2a[tid] + w2col[tid]*sb;
    {   // gather only active rows (fp32 -> bf16 LDS, stride 136)
        int r = tid >> 2, sg = tid & 3;
        if (r < ntile*16){
            long nb = neighbors[b*64 + r];
            const float4* sp = (const float4*)(node_pre + nb*128 + sg*32);
#pragma unroll
            for (int q = 0; q < 4; ++q){
                float4 fa = sp[q*2], fb = sp[q*2+1];
                *(bf16x8*)&at[r*136 + sg*32 + q*8] = pack8(fa, fb);
            }
        }
    }

    int wave = tid >> 6, lane = tid & 63, quad = lane >> 4, l15 = lane & 15;
    const bf16x8* FB = (const bf16x8*)(wsbf + EL_W2A);
    bf16x8 bw[16];   // wave's 4 n-tiles x 4 k-steps, held in registers
#pragma unroll
    for (int j = 0; j < 4; ++j){
        int nt = wave + 4*j;
#pragma unroll
        for (int kk = 0; kk < 4; ++kk) bw[j*4+kk] = FB[(nt*4+kk)*64 + lane];
    }
    __syncthreads();

#pragma unroll 1
    for (int mt = 0; mt < ntile; ++mt){
        bf16x8 af[4];
#pragma unroll
        for (int kk = 0; kk < 4; ++kk)
            af[kk] = *(const bf16x8*)&at[(mt*16 + l15)*136 + kk*32 + quad*8];
        f32x4 ps = {0.f,0.f,0.f,0.f};
#pragma unroll
        for (int j = 0; j < 4; ++j){
            int nt = wave + 4*j;
            f32x4 acc = {0.f,0.f,0.f,0.f};
#pragma unroll
            for (int kk = 0; kk < 4; ++kk)
                acc = __builtin_amdgcn_mfma_f32_16x16x32_bf16(af[kk], bw[j*4+kk], acc, 0,0,0);
            int col = nt*16 + l15;
            float bb = bias_s[col], tv = t_s[col];
#pragma unroll
            for (int i = 0; i < 4; ++i)
                ps[i] += fmaxf(acc[i] + bb, 0.f) * tv;
        }
#pragma unroll
        for (int m = 1; m < 16; m <<= 1){
#pragma unroll
            for (int i = 0; i < 4; ++i) ps[i] += __shfl_xor(ps[i], m, 64);
        }
        if (l15 == 0){
#pragma unroll
            for (int i = 0; i < 4; ++i) vp[wave*64 + mt*16 + quad*4 + i] = ps[i];
        }
    }
    __syncthreads();
    if (tid < 64){
        // rows >= ntile*16 read stale vp but are masked to 0 below
        float v = vp[tid] + vp[64+tid] + vp[128+tid] + vp[192+tid];
        v = (v + const_ws[b]) * 0.08838834764831845f;   // 1/sqrt(128)
        if (tid >= degb) v = 0.f;
        out_vals[(long)b*64 + tid] = v;
    }
}

extern "C" void kernel_launch(void* const* d_in, const int* in_sizes, int n_in,
                              void* d_out, int out_size, void* d_ws, size_t ws_size,
                              hipStream_t stream)
{
    (void)in_sizes; (void)n_in; (void)out_size; (void)ws_size;
    const float* node_pre = (const float*)d_in[0];
    const float* steps    = (const float*)d_in[1];
    const float* h0       = (const float*)d_in[2];
    const float* c0       = (const float*)d_in[3];
    const float* W1a      = (const float*)d_in[4];
    const float* b1a      = (const float*)d_in[5];
    const float* W1b      = (const float*)d_in[6];
    const float* b1b      = (const float*)d_in[7];
    const float* W2a      = (const float*)d_in[8];
    const float* b2a      = (const float*)d_in[9];
    const float* W2b      = (const float*)d_in[10];
    const float* b2b      = (const float*)d_in[11];
    const float* W3       = (const float*)d_in[12];
    const float* b3       = (const float*)d_in[13];
    const float* Wih      = (const float*)d_in[14];
    const float* Whh      = (const float*)d_in[15];
    const float* bih      = (const float*)d_in[16];
    const float* bhh      = (const float*)d_in[17];
    const int* actions0   = (const int*)d_in[18];
    const int* neighbors  = (const int*)d_in[19];
    const int* deg        = (const int*)d_in[20];

    float* out      = (float*)d_out;
    float* out_vals = out;                       // [4096][64]
    float* out_h    = out + (long)BB*KK;         // [4096][256]
    float* out_c    = out_h + (long)BB*HH;       // [4096][256]

    __bf16* wsbf     = (__bf16*)d_ws;
    float* gb_ws     = (float*)((char*)d_ws + BOFF_GB);
    float* w1col_ws  = (float*)((char*)d_ws + BOFF_W1COL);
    float* w2col_ws  = (float*)((char*)d_ws + BOFF_W2COL);
    float* const_ws  = (float*)((char*)d_ws + BOFF_CONST);
    __bf16* x1_bf    = (__bf16*)((char*)d_ws + BOFF_X1);
    __bf16* x_bf     = (__bf16*)((char*)d_ws + BOFF_X);
    __bf16* h0_bf    = (__bf16*)((char*)d_ws + BOFF_H0B);
    __bf16* h_bf     = (__bf16*)((char*)d_ws + BOFF_HB);
    __bf16* emb_bf   = (__bf16*)((char*)d_ws + BOFF_EMB);
    __bf16* t_bf     = (__bf16*)((char*)d_ws + BOFF_T);

    swz_kernel<<<dim3(3160), dim3(64), 0, stream>>>(W1a, W1b, Wih, Whh, W3, W2b, W2a,
                                                    bih, bhh, h0, wsbf, gb_ws,
                                                    w1col_ws, w2col_ws, h0_bf);
    s1_kernel<<<dim3(1024), dim3(64), 0, stream>>>(node_pre, steps, actions0, b1a,
                                                   w1col_ws, wsbf, x1_bf);
    s2_kernel<<<dim3(1024), dim3(64), 0, stream>>>(x1_bf, b1b, wsbf, x_bf);
    lstm_kernel<<<dim3(4096), dim3(64), 0, stream>>>(x_bf, h0_bf, c0, gb_ws, wsbf,
                                                     out_h, out_c, h_bf);
    s4_kernel<<<dim3(1024), dim3(64), 0, stream>>>(h_bf, b3, wsbf, emb_bf);
    s5_kernel<<<dim3(1024), dim3(64), 0, stream>>>(emb_bf, b2b, wsbf, t_bf, const_ws);
    nei_kernel<<<dim3(4096), dim3(256), 0, stream>>>(node_pre, steps, b2a, w2col_ws,
                                                     neighbors, deg, wsbf, t_bf, const_ws,
                                                     out_vals);
}